// Round 9
// baseline (314.276 us; speedup 1.0000x reference)
//
#include <hip/hip_runtime.h>
#include <cmath>
#include <cstdint>

// ---------------- static configuration ----------------
// B=32, T=4096, C=3, 128 scales, out 224x224, N_PSI=4096, pad=2047.
// slot = c*32 + b (96 real, padded to 128), padded signal length 8190.
// Composite kernel per (scale, class): class 0..6 = interior phase (w mod 7),
// class 7 = w==0 (left-clipped), class 8 = w==223 (right-clipped).
// H rows: [160 zero guard][<=3310 data, 4-aligned][>=300 zero guard], stride 3776.
// xpT[m][slot]: plain transposed layout; 4 consecutive slots = one v4f.
//
// Round 9 structure: block = 1 wave, RW=8 consecutive w (union = rl+~136,
// 1.8x fewer m-units than RW=4), HALF-WAVE M-SPLIT: lanes 0-31 process the
// first half of the piece's m-range, lanes 32-63 the second; each half-wave
// covers all 128 slots at 4 slots/lane (v4f = 2 packed pairs). Each H b128
// broadcast now feeds 8 packed FMAs/lane -> LDS return bytes per FMA halved
// vs r8 (which sat ON the LDS wall: 112us model vs 126 measured). Halves
// combined with shfl_xor(32) before fp32 atomicAdd into OT.

constexpr int C_TP     = 8190;
constexpr int C_XROWS  = 8192;   // time rows in xpT
constexpr long long C_HSTRIDE = 3776;
constexpr int C_HGUARD = 160;
constexpr int C_NCLS   = 9;
constexpr int C_RW     = 8;      // w's per block (consecutive)
constexpr int C_NCH    = 28;     // 224 / C_RW
constexpr int C_NW     = 224;
constexpr int C_SIGP   = 128;    // padded slots
constexpr int C_M      = 256;    // m per piece
constexpr int C_NP     = 14;     // max pieces
constexpr int C_SQ     = 64;     // staged quads per row (C_M/4)

typedef float v2f __attribute__((ext_vector_type(2)));
typedef float v4f __attribute__((ext_vector_type(4)));

// Replicate numpy: scales = logspace(log10(2), log10(204), 128).astype(f32);
// K = ceil(16*s + 1); d = (4094-K)//2; a = s * (16/4095) in double.
__device__ __forceinline__ void scale_params(int i, float& s32, int& K, int& d, double& a) {
  const double l2   = log10(2.0);
  const double l204 = log10(204.0);
  double step = (l204 - l2) / 127.0;
  double e = (i == 127) ? l204 : ((double)i * step + l2);
  double sv = pow(10.0, e);
  s32 = (float)sv;
  double sp = (double)s32;
  K = (int)ceil(sp * 16.0 + 1.0);
  d = (4094 - K) >> 1;
  a = sp * (16.0 / 4095.0);
}

// ---------------- build composite kernels H (+fused OT zero & xpT build) -------------
// grid (128, 10): cls<9 -> H row; cls==9 -> zero OT strip + build xpT strip.
__global__ __launch_bounds__(256) void k_build_H(const float* __restrict__ int_psi,
                                                 const float* __restrict__ x,
                                                 float* __restrict__ Hbuf,
                                                 int* __restrict__ meta,
                                                 float* __restrict__ xpT,
                                                 float* __restrict__ OT) {
  int i   = blockIdx.x;   // scale (or strip index for cls==9)
  int cls = blockIdx.y;   // class

  if (cls == 9) {
    // zero OT strip: 128 strips x 7168 float4
    float4* otz = (float4*)OT + (long long)i * 7168;
    float4 z4 = make_float4(0.f, 0.f, 0.f, 0.f);
    for (int q = threadIdx.x; q < 7168; q += 256) otz[q] = z4;
    // build xpT strip: 128 strips x 8192 floats; xpT[p][slot], reflect pad
    for (int q = threadIdx.x; q < 8192; q += 256) {
      int idx  = i * 8192 + q;
      int slot = idx & 127;
      int p    = idx >> 7;
      float val = 0.f;
      if (slot < 96 && p < C_TP) {
        int c = slot >> 5;
        int b = slot & 31;
        int t = p - 2047;
        if (t < 0) t = -t;                 // x[2047-p]
        else if (t > 4095) t = 8190 - t;   // x[10237-p]
        val = x[(b * 4096 + t) * 3 + c];
      }
      xpT[idx] = val;
    }
    return;
  }

  float s32; int K, d; double a;
  scale_params(i, s32, K, d, a);

  int wr = (cls < 7) ? ((cls == 0) ? 7 : cls) : ((cls == 7) ? 0 : 223);
  double ks = 4096.0 / 224.0;
  double sf = ((double)wr + 0.5) * ks - 0.5;
  int t_lo = (int)floor(sf - ks) + 1;
  int t_hi = (int)ceil(sf + ks) - 1;
  if (t_lo < 0) t_lo = 0;
  if (t_hi > 4095) t_hi = 4095;
  int nt  = t_hi - t_lo + 1;   // <= 37
  int npv = nt + 1;            // conv-point weights

  __shared__ double Wt_sh[40];
  __shared__ double v_sh[64];
  __shared__ float  kern_sh[3352];

  // zero this block's full row
  float* rowFull = Hbuf + (long long)(i * C_NCLS + cls) * C_HSTRIDE;
  for (int q = threadIdx.x; q < (int)C_HSTRIDE; q += 256) rowFull[q] = 0.f;

  if (threadIdx.x == 0) {
    double Z = 0.0;
    for (int t = 0; t < nt; ++t) {
      double wv = 1.0 - fabs(sf - (double)(t + t_lo)) / ks;
      if (wv < 0.0) wv = 0.0;
      Wt_sh[t] = wv; Z += wv;
    }
    for (int t = 0; t < nt; ++t) Wt_sh[t] = Wt_sh[t] / Z;
    double sq = sqrt((double)s32);
    // v[p_lo + q] = -sqrt(s) * (Wt[q-1] - Wt[q])
    for (int q = 0; q <= nt; ++q) {
      double wm1 = (q >= 1)  ? Wt_sh[q - 1] : 0.0;
      double w0  = (q < nt)  ? Wt_sh[q]     : 0.0;
      v_sh[q] = -sq * (wm1 - w0);
    }
  }

  // flipped gathered wavelet: kernW[tau] = int_psi[clip(floor((K-1-tau)/a))]
  float* kernp = kern_sh + 40;
  int fillN = K + 80;
  for (int q = threadIdx.x; q < fillN; q += 256) {
    int tau = q - 40;
    float kv = 0.f;
    if (tau >= 0 && tau < K) {
      int u = K - 1 - tau;
      int jj = (int)floor((double)u / a);
      jj = jj < 0 ? 0 : (jj > 4095 ? 4095 : jj);
      kv = int_psi[jj];
    }
    kern_sh[q] = kv;
  }
  __syncthreads();

  int p_lo = t_lo + d;
  int Lh   = K + npv - 1;
  int kr   = (cls == 0) ? 1 : ((cls == 8) ? 31 : 0);
  int off0 = p_lo - 128 * kr;
  int shift = off0 & 3;
  int offA  = off0 - shift;
  int rowLen = (shift + Lh + 3) & ~3;

  float* row = Hbuf + (long long)(i * C_NCLS + cls) * C_HSTRIDE + C_HGUARD;
  for (int q = threadIdx.x; q < Lh; q += 256) {
    double acc = 0.0;
    for (int t = 0; t < npv; ++t) acc += v_sh[t] * (double)kernp[q - t];
    row[shift + q] = (float)acc;
  }
  if (threadIdx.x == 0) {
    meta[(i * C_NCLS + cls) * 2 + 0] = offA;
    meta[(i * C_NCLS + cls) * 2 + 1] = rowLen;
  }
}

// ---------------- main: OT[scale][w][slot] += sum_{m in piece} xpT[m][slot]*H_w[m] ------
// grid (piece, chunk, scale'), scale' reversed so heavy scales dispatch first.
// ONE wave; half-wave m-split; lane owns slots 4g..4g+3 (g = lane&31).
__global__ __launch_bounds__(64, 4) void k_cwt_main(const float* __restrict__ xpT,
                                                    const float* __restrict__ Hbuf,
                                                    const int* __restrict__ meta,
                                                    float* __restrict__ OT) {
  int piece = blockIdx.x;           // 0..13
  int chunk = blockIdx.y;           // 0..27
  int i     = 127 - blockIdx.z;     // heavy scales first
  int lane  = threadIdx.x;          // 0..63
  int g     = lane & 31;
  int half  = lane >> 5;

  __shared__ v4f Hs[C_RW][C_SQ];    // 8 KB

  v2f accL[C_RW], accH[C_RW];
  const float* rowP[C_RW];
  int startj[C_RW];
  int U0 = 0x7fffffff, U1 = 0;
#pragma unroll
  for (int j = 0; j < C_RW; ++j) {
    accL[j] = (v2f){0.f, 0.f};
    accH[j] = (v2f){0.f, 0.f};
    int w = chunk * C_RW + j;
    int cls = (w == 0) ? 7 : ((w == 223) ? 8 : (w % 7));
    int k = w / 7;
    int base = i * C_NCLS + cls;
    int offA = meta[base * 2 + 0];
    int rl   = meta[base * 2 + 1];
    int start = offA + 128 * k;           // 4-aligned by construction
    startj[j] = start;
    if (start < U0) U0 = start;
    if (start + rl > U1) U1 = start + rl;
    rowP[j] = Hbuf + (long long)base * C_HSTRIDE;
  }

  int m0 = U0 + piece * C_M;
  int m1 = m0 + C_M; if (m1 > U1) m1 = U1;
  if (m0 >= m1) return;                  // uniform across block

  int len = m1 - m0;
  int nIt = (len + 7) >> 3;              // 4-m steps per half-wave (<=32)
  int sQ  = 2 * nIt;                     // staged quads per row (<=64)

  // ---- stage H piece into LDS ----
  // staged float idx within row <= HGUARD + (m1+7 - start_j) - 1 <= 3622 < 3776:
  // always data or zero guard, never out of the row. relS >= 160-136 > 0.
#pragma unroll
  for (int j = 0; j < C_RW; ++j) {
    const float* src = rowP[j] + (C_HGUARD + m0 - startj[j]);
    for (int q = lane; q < sQ; q += 64)
      Hs[j][q] = *(const v4f*)(src + 4 * q);
  }
  __syncthreads();

  // ---- inner loop: per half-wave 4 m/step; x on vmcnt, H broadcast on lgkmcnt ----
  // Each lane: 4 slots (2 packed pairs) x 4 m x 8 w = 64 v_pk_fma per step.
  const float* xr = xpT + ((long long)(m0 + 4 * nIt * half) << 7) + (g << 2);
  int hq = half * nIt;
  for (int it = 0; it < nIt; ++it) {
    v4f xv0 = *(const v4f*)(xr);
    v4f xv1 = *(const v4f*)(xr + 128);
    v4f xv2 = *(const v4f*)(xr + 256);
    v4f xv3 = *(const v4f*)(xr + 384);
    xr += 512;
#pragma unroll
    for (int j = 0; j < C_RW; ++j) {
      v4f h = Hs[j][hq + it];
      accL[j] += xv0.xy * h.x; accH[j] += xv0.zw * h.x;
      accL[j] += xv1.xy * h.y; accH[j] += xv1.zw * h.y;
      accL[j] += xv2.xy * h.z; accH[j] += xv2.zw * h.z;
      accL[j] += xv3.xy * h.w; accH[j] += xv3.zw * h.w;
    }
  }

  // ---- combine halves, then fp32 atomics (lanes 0-31 only) ----
#pragma unroll
  for (int j = 0; j < C_RW; ++j) {
    float s0 = accL[j].x, s1 = accL[j].y, s2 = accH[j].x, s3 = accH[j].y;
    s0 += __shfl_xor(s0, 32);
    s1 += __shfl_xor(s1, 32);
    s2 += __shfl_xor(s2, 32);
    s3 += __shfl_xor(s3, 32);
    if (lane < 32) {
      int w = chunk * C_RW + j;
      float* dst = OT + ((long long)i * C_NW + w) * C_SIGP + (g << 2);
      atomicAdd(dst + 0, s0);
      atomicAdd(dst + 1, s1);
      atomicAdd(dst + 2, s2);
      atomicAdd(dst + 3, s3);
    }
  }
}

// ---------------- final: scale-dim bilinear upsample 128->224 + layout ----------------
__global__ __launch_bounds__(256) void k_final(const float* __restrict__ OT,
                                               float* __restrict__ out) {
  int wt = blockIdx.x;    // 0..27
  int h  = blockIdx.y;    // 0..223

  float inv = 128.0f / 224.0f;               // f32 like jax
  float sg = ((float)h + 0.5f) * inv - 0.5f;
  float sgf = floorf(sg);
  int s0 = (int)sgf;
  float fr = sg - sgf;
  int r0, r1;
  if (s0 < 0)        { r0 = 0;   r1 = 0;   fr = 0.f; }
  else if (s0 >= 127){ r0 = 127; r1 = 127; fr = 0.f; }
  else               { r0 = s0;  r1 = s0 + 1; }

  __shared__ float sh0[8 * 132];
  __shared__ float sh1[8 * 132];
  for (int q = threadIdx.x; q < 1024; q += 256) {
    int wp  = q >> 7;
    int sg2 = q & 127;
    int wg  = wt * 8 + wp;
    sh0[wp * 132 + sg2] = OT[((long long)r0 * C_NW + wg) * C_SIGP + sg2];
    sh1[wp * 132 + sg2] = OT[((long long)r1 * C_NW + wg) * C_SIGP + sg2];
  }
  __syncthreads();

  int b  = threadIdx.x >> 3;    // 0..31
  int wp = threadIdx.x & 7;     // 0..7
  int obase = ((b * 224 + h) * 224 + wt * 8 + wp) * 3;
#pragma unroll
  for (int c = 0; c < 3; ++c) {
    int sidx = wp * 132 + c * 32 + b;
    float a0 = sh0[sidx];
    float a1 = sh1[sidx];
    out[obase + c] = (1.0f - fr) * a0 + fr * a1;
  }
}

// ---------------- launch ----------------
extern "C" void kernel_launch(void* const* d_in, const int* in_sizes, int n_in,
                              void* d_out, int out_size, void* d_ws, size_t ws_size,
                              hipStream_t stream) {
  const float* x       = (const float*)d_in[0];   // (32,4096,3) f32
  const float* int_psi = (const float*)d_in[1];   // (4096,) f32
  float* out = (float*)d_out;

  // workspace layout: xpT (4 MB) | Hbuf (17.4 MB) | meta (9 KB) | OT (14.7 MB)
  float* xpT  = (float*)d_ws;                                   // 8192*128 floats
  float* Hbuf = xpT + (long long)C_XROWS * C_SIGP;              // 1152*3776 floats
  int*   meta = (int*)(Hbuf + (long long)128 * C_NCLS * C_HSTRIDE); // 2304 ints
  float* OT   = (float*)(meta + 2304);                          // 128*224*128 floats

  k_build_H<<<dim3(128, 10), dim3(256), 0, stream>>>(int_psi, x, Hbuf, meta, xpT, OT);
  k_cwt_main<<<dim3(C_NP, C_NCH, 128), dim3(64), 0, stream>>>(xpT, Hbuf, meta, OT);
  k_final<<<dim3(28, 224), dim3(256), 0, stream>>>(OT, out);
}

// Round 10
// 207.270 us; speedup vs baseline: 1.5163x; 1.5163x over previous
//
#include <hip/hip_runtime.h>
#include <cmath>
#include <cstdint>

// ---------------- static configuration ----------------
// B=32, T=4096, C=3, 128 scales, out 224x224, N_PSI=4096, pad=2047.
// slot = c*32 + b (96 real, padded to 128), padded signal length 8190.
// Composite kernel per (scale, class): class 0..6 = interior phase (w mod 7),
// class 7 = w==0 (left-clipped), class 8 = w==223 (right-clipped).
// H rows: [160 zero guard][<=3314 data, 4-aligned][>=300 zero guard], stride 3776.
//
// x layout: SLOT-INTERLEAVED xpQ[m][g*4+e] = xp[m][g + 32*e], g in [0,32), e in [0,4).
// Lane g loads one v4f = slots {g, g+32, g+64, g+96} at time m (2 packed pairs),
// AND the per-e combined outputs across lanes 0-31 are 32 contiguous OT words ->
// coalesced atomic batches (r9's 16B-strided atomic scatter caused 221 MB of
// write-through traffic ~= the whole 218 us runtime; r8's contiguous pattern = 30 MB).
//
// Main kernel: 1 wave, RW=8 consecutive w, HALF-WAVE M-SPLIT (lanes 0-31 take the
// piece's first 4*nIt m, lanes 32-63 the second): each H b128 broadcast feeds
// 8 packed FMAs/lane -> ~1 B LDS per MAC. C_M=512 (pieces<=7) keeps atomic
// volume at r8's level. Halves combined with shfl_xor(32) before atomics.

constexpr int C_TP     = 8190;
constexpr int C_XROWS  = 8192;   // time rows in xpQ
constexpr long long C_HSTRIDE = 3776;
constexpr int C_HGUARD = 160;
constexpr int C_NCLS   = 9;
constexpr int C_RW     = 8;      // w's per block (consecutive)
constexpr int C_NCH    = 28;     // 224 / C_RW
constexpr int C_NW     = 224;
constexpr int C_SIGP   = 128;    // padded slots
constexpr int C_M      = 512;    // m per piece
constexpr int C_NP     = 7;      // max pieces: ceil((3314+136)/512)
constexpr int C_SQ     = 128;    // staged quads per row (C_M/4)

typedef float v2f __attribute__((ext_vector_type(2)));
typedef float v4f __attribute__((ext_vector_type(4)));

// Replicate numpy: scales = logspace(log10(2), log10(204), 128).astype(f32);
// K = ceil(16*s + 1); d = (4094-K)//2; a = s * (16/4095) in double.
__device__ __forceinline__ void scale_params(int i, float& s32, int& K, int& d, double& a) {
  const double l2   = log10(2.0);
  const double l204 = log10(204.0);
  double step = (l204 - l2) / 127.0;
  double e = (i == 127) ? l204 : ((double)i * step + l2);
  double sv = pow(10.0, e);
  s32 = (float)sv;
  double sp = (double)s32;
  K = (int)ceil(sp * 16.0 + 1.0);
  d = (4094 - K) >> 1;
  a = sp * (16.0 / 4095.0);
}

// ---------------- build composite kernels H (+fused OT zero & xpQ build) -------------
// grid (128, 10): cls<9 -> H row; cls==9 -> zero OT strip + build xpQ strip.
__global__ __launch_bounds__(256) void k_build_H(const float* __restrict__ int_psi,
                                                 const float* __restrict__ x,
                                                 float* __restrict__ Hbuf,
                                                 int* __restrict__ meta,
                                                 float* __restrict__ xpQ,
                                                 float* __restrict__ OT) {
  int i   = blockIdx.x;   // scale (or strip index for cls==9)
  int cls = blockIdx.y;   // class

  if (cls == 9) {
    // zero OT strip: 128 strips x 7168 float4
    float4* otz = (float4*)OT + (long long)i * 7168;
    float4 z4 = make_float4(0.f, 0.f, 0.f, 0.f);
    for (int q = threadIdx.x; q < 7168; q += 256) otz[q] = z4;
    // build xpQ strip: 128 strips x 8192 floats; slot-interleaved, reflect pad
    for (int q = threadIdx.x; q < 8192; q += 256) {
      int idx = i * 8192 + q;
      int r   = idx & 127;
      int p   = idx >> 7;
      int g   = r >> 2;       // b
      int e   = r & 3;        // c (e==3 -> pad)
      float val = 0.f;
      if (e < 3 && p < C_TP) {
        int t = p - 2047;
        if (t < 0) t = -t;                 // x[2047-p]
        else if (t > 4095) t = 8190 - t;   // x[10237-p]
        val = x[(g * 4096 + t) * 3 + e];
      }
      xpQ[idx] = val;
    }
    return;
  }

  float s32; int K, d; double a;
  scale_params(i, s32, K, d, a);

  int wr = (cls < 7) ? ((cls == 0) ? 7 : cls) : ((cls == 7) ? 0 : 223);
  double ks = 4096.0 / 224.0;
  double sf = ((double)wr + 0.5) * ks - 0.5;
  int t_lo = (int)floor(sf - ks) + 1;
  int t_hi = (int)ceil(sf + ks) - 1;
  if (t_lo < 0) t_lo = 0;
  if (t_hi > 4095) t_hi = 4095;
  int nt  = t_hi - t_lo + 1;   // <= 37
  int npv = nt + 1;            // conv-point weights

  __shared__ double Wt_sh[40];
  __shared__ float  v_shf[40];
  __shared__ float  kern_sh[3352];

  // zero this block's full row
  float* rowFull = Hbuf + (long long)(i * C_NCLS + cls) * C_HSTRIDE;
  for (int q = threadIdx.x; q < (int)C_HSTRIDE; q += 256) rowFull[q] = 0.f;

  if (threadIdx.x == 0) {
    double Z = 0.0;
    for (int t = 0; t < nt; ++t) {
      double wv = 1.0 - fabs(sf - (double)(t + t_lo)) / ks;
      if (wv < 0.0) wv = 0.0;
      Wt_sh[t] = wv; Z += wv;
    }
    for (int t = 0; t < nt; ++t) Wt_sh[t] = Wt_sh[t] / Z;
    double sq = sqrt((double)s32);
    // v[p_lo + q] = -sqrt(s) * (Wt[q-1] - Wt[q])   (weights built in double, used f32)
    for (int q = 0; q < 40; ++q) {
      double wm1 = (q >= 1 && q <= nt)  ? Wt_sh[q - 1] : 0.0;
      double w0  = (q < nt)             ? Wt_sh[q]     : 0.0;
      v_shf[q] = (float)(-sq * (wm1 - w0));
    }
  }

  // flipped gathered wavelet: kernW[tau] = int_psi[clip(floor((K-1-tau)/a))]
  float* kernp = kern_sh + 40;
  int fillN = K + 80;
  for (int q = threadIdx.x; q < fillN; q += 256) {
    int tau = q - 40;
    float kv = 0.f;
    if (tau >= 0 && tau < K) {
      int u = K - 1 - tau;
      int jj = (int)floor((double)u / a);
      jj = jj < 0 ? 0 : (jj > 4095 ? 4095 : jj);
      kv = int_psi[jj];
    }
    kern_sh[q] = kv;
  }
  __syncthreads();

  int p_lo = t_lo + d;
  int Lh   = K + npv - 1;
  int kr   = (cls == 0) ? 1 : ((cls == 8) ? 31 : 0);
  int off0 = p_lo - 128 * kr;
  int shift = off0 & 3;
  int offA  = off0 - shift;
  int rowLen = (shift + Lh + 3) & ~3;

  float* row = Hbuf + (long long)(i * C_NCLS + cls) * C_HSTRIDE + C_HGUARD;
  for (int q = threadIdx.x; q < Lh; q += 256) {
    float acc = 0.f;
    for (int t = 0; t < npv; ++t) acc += v_shf[t] * kernp[q - t];
    row[shift + q] = acc;
  }
  if (threadIdx.x == 0) {
    meta[(i * C_NCLS + cls) * 2 + 0] = offA;
    meta[(i * C_NCLS + cls) * 2 + 1] = rowLen;
  }
}

// ---------------- main: OT[scale][w][slot] += sum_{m in piece} xp[m][slot]*H_w[m] ------
// grid (piece, chunk, scale'), scale' reversed so heavy scales dispatch first.
// ONE wave; half-wave m-split; lane owns slots {g, g+32, g+64, g+96} (g = lane&31).
__global__ __launch_bounds__(64, 4) void k_cwt_main(const float* __restrict__ xpQ,
                                                    const float* __restrict__ Hbuf,
                                                    const int* __restrict__ meta,
                                                    float* __restrict__ OT) {
  int piece = blockIdx.x;           // 0..6
  int chunk = blockIdx.y;           // 0..27
  int i     = 127 - blockIdx.z;     // heavy scales first
  int lane  = threadIdx.x;          // 0..63
  int g     = lane & 31;
  int half  = lane >> 5;

  __shared__ v4f Hs[C_RW][C_SQ];    // 16 KB

  v2f accL[C_RW], accH[C_RW];
  const float* rowP[C_RW];
  int startj[C_RW];
  int U0 = 0x7fffffff, U1 = 0;
#pragma unroll
  for (int j = 0; j < C_RW; ++j) {
    accL[j] = (v2f){0.f, 0.f};
    accH[j] = (v2f){0.f, 0.f};
    int w = chunk * C_RW + j;
    int cls = (w == 0) ? 7 : ((w == 223) ? 8 : (w % 7));
    int k = w / 7;
    int base = i * C_NCLS + cls;
    int offA = meta[base * 2 + 0];
    int rl   = meta[base * 2 + 1];
    int start = offA + 128 * k;           // 4-aligned by construction
    startj[j] = start;
    if (start < U0) U0 = start;
    if (start + rl > U1) U1 = start + rl;
    rowP[j] = Hbuf + (long long)base * C_HSTRIDE;
  }

  int m0 = U0 + piece * C_M;
  int m1 = m0 + C_M; if (m1 > U1) m1 = U1;
  if (m0 >= m1) return;                  // uniform across block

  int len = m1 - m0;
  int nIt = (len + 7) >> 3;              // 4-m steps per half-wave (<=64)
  int sQ  = 2 * nIt;                     // staged quads per row (<=128)

  // ---- stage H piece into LDS ----
  // staged float idx within row: relS in [24, 3232+160]; max idx <= 3743 < 3776:
  // always row data or zero guard. Overread in m (up to m1+7) also guard-covered.
#pragma unroll
  for (int j = 0; j < C_RW; ++j) {
    const float* src = rowP[j] + (C_HGUARD + m0 - startj[j]);
    for (int q = lane; q < sQ; q += 64)
      Hs[j][q] = *(const v4f*)(src + 4 * q);
  }
  __syncthreads();

  // ---- inner loop: per half-wave 4 m/step; x on vmcnt, H broadcast on lgkmcnt ----
  // Lane: 4 slots (2 packed pairs) x 4 m x 8 w = 64 v_pk_fma per step.
  const float* xr = xpQ + ((long long)(m0 + 4 * nIt * half) << 7) + (g << 2);
  int hq = half * nIt;
  for (int it = 0; it < nIt; ++it) {
    v4f xv0 = *(const v4f*)(xr);
    v4f xv1 = *(const v4f*)(xr + 128);
    v4f xv2 = *(const v4f*)(xr + 256);
    v4f xv3 = *(const v4f*)(xr + 384);
    xr += 512;
#pragma unroll
    for (int j = 0; j < C_RW; ++j) {
      v4f h = Hs[j][hq + it];
      accL[j] += xv0.xy * h.x; accH[j] += xv0.zw * h.x;
      accL[j] += xv1.xy * h.y; accH[j] += xv1.zw * h.y;
      accL[j] += xv2.xy * h.z; accH[j] += xv2.zw * h.z;
      accL[j] += xv3.xy * h.w; accH[j] += xv3.zw * h.w;
    }
  }

  // ---- combine halves, then coalesced fp32 atomics (lanes 0-31, 4 batches of 32) ----
#pragma unroll
  for (int j = 0; j < C_RW; ++j) {
    float s0 = accL[j].x, s1 = accL[j].y, s2 = accH[j].x, s3 = accH[j].y;
    s0 += __shfl_xor(s0, 32);
    s1 += __shfl_xor(s1, 32);
    s2 += __shfl_xor(s2, 32);
    s3 += __shfl_xor(s3, 32);
    if (lane < 32) {
      int w = chunk * C_RW + j;
      float* dst = OT + ((long long)i * C_NW + w) * C_SIGP;
      atomicAdd(dst + g,      s0);     // slots  0..31  contiguous across lanes
      atomicAdd(dst + 32 + g, s1);     // slots 32..63
      atomicAdd(dst + 64 + g, s2);     // slots 64..95
      atomicAdd(dst + 96 + g, s3);     // slots 96..127 (pad)
    }
  }
}

// ---------------- final: scale-dim bilinear upsample 128->224 + layout ----------------
__global__ __launch_bounds__(256) void k_final(const float* __restrict__ OT,
                                               float* __restrict__ out) {
  int wt = blockIdx.x;    // 0..27
  int h  = blockIdx.y;    // 0..223

  float inv = 128.0f / 224.0f;               // f32 like jax
  float sg = ((float)h + 0.5f) * inv - 0.5f;
  float sgf = floorf(sg);
  int s0 = (int)sgf;
  float fr = sg - sgf;
  int r0, r1;
  if (s0 < 0)        { r0 = 0;   r1 = 0;   fr = 0.f; }
  else if (s0 >= 127){ r0 = 127; r1 = 127; fr = 0.f; }
  else               { r0 = s0;  r1 = s0 + 1; }

  __shared__ float sh0[8 * 132];
  __shared__ float sh1[8 * 132];
  for (int q = threadIdx.x; q < 1024; q += 256) {
    int wp  = q >> 7;
    int sg2 = q & 127;
    int wg  = wt * 8 + wp;
    sh0[wp * 132 + sg2] = OT[((long long)r0 * C_NW + wg) * C_SIGP + sg2];
    sh1[wp * 132 + sg2] = OT[((long long)r1 * C_NW + wg) * C_SIGP + sg2];
  }
  __syncthreads();

  int b  = threadIdx.x >> 3;    // 0..31
  int wp = threadIdx.x & 7;     // 0..7
  int obase = ((b * 224 + h) * 224 + wt * 8 + wp) * 3;
#pragma unroll
  for (int c = 0; c < 3; ++c) {
    int sidx = wp * 132 + c * 32 + b;
    float a0 = sh0[sidx];
    float a1 = sh1[sidx];
    out[obase + c] = (1.0f - fr) * a0 + fr * a1;
  }
}

// ---------------- launch ----------------
extern "C" void kernel_launch(void* const* d_in, const int* in_sizes, int n_in,
                              void* d_out, int out_size, void* d_ws, size_t ws_size,
                              hipStream_t stream) {
  const float* x       = (const float*)d_in[0];   // (32,4096,3) f32
  const float* int_psi = (const float*)d_in[1];   // (4096,) f32
  float* out = (float*)d_out;

  // workspace layout: xpQ (4 MB) | Hbuf (17.4 MB) | meta (9 KB) | OT (14.7 MB)
  float* xpQ  = (float*)d_ws;                                   // 8192*128 floats
  float* Hbuf = xpQ + (long long)C_XROWS * C_SIGP;              // 1152*3776 floats
  int*   meta = (int*)(Hbuf + (long long)128 * C_NCLS * C_HSTRIDE); // 2304 ints
  float* OT   = (float*)(meta + 2304);                          // 128*224*128 floats

  k_build_H<<<dim3(128, 10), dim3(256), 0, stream>>>(int_psi, x, Hbuf, meta, xpQ, OT);
  k_cwt_main<<<dim3(C_NP, C_NCH, 128), dim3(64), 0, stream>>>(xpQ, Hbuf, meta, OT);
  k_final<<<dim3(28, 224), dim3(256), 0, stream>>>(OT, out);
}

// Round 11
// 205.072 us; speedup vs baseline: 1.5325x; 1.0107x over previous
//
#include <hip/hip_runtime.h>
#include <cmath>
#include <cstdint>

// ---------------- static configuration ----------------
// B=32, T=4096, C=3, 128 scales, out 224x224, N_PSI=4096, pad=2047.
// slot = c*32 + b (96 real, padded to 128), padded signal length 8190.
// Composite kernel per (scale, class): class 0..6 = interior phase (w mod 7),
// class 7 = w==0 (left-clipped), class 8 = w==223 (right-clipped).
// H rows: [160 zero guard][<=3314 data, 4-aligned][>=300 zero guard], stride 3776.
//
// x layout: SLOT-INTERLEAVED xpQ[m][g*4+e] = xp[m][g + 32*e], g in [0,32), e in [0,4).
// Lane g loads one v4f = slots {g, g+32, g+64, g+96} at time m (2 packed pairs),
// and per-e combined outputs across lanes 0-31 are 32 contiguous OT words ->
// coalesced atomic batches (r9's strided scatter cost 221 MB write-through; r10
// fixed it: 31 MB, 218 -> 116 us).
//
// Round 11: r10 was latency-bound at 1.7 waves/SIMD (16 KB LDS -> 10 blocks/CU;
// VALU 56us / LDS-return 62us / x-L2 47us all at ~50% duty). Two-phase staging
// halves LDS to 8 KB -> 19 blocks/CU. Half-wave m-split moved to iteration
// granularity (half A: m0+8it+0..3, half B: +4..7) so H quads are consumed
// in order (2it, 2it+1) and each 64-quad phase is self-contained.

constexpr int C_TP     = 8190;
constexpr int C_XROWS  = 8192;   // time rows in xpQ
constexpr long long C_HSTRIDE = 3776;
constexpr int C_HGUARD = 160;
constexpr int C_NCLS   = 9;
constexpr int C_RW     = 8;      // w's per block (consecutive)
constexpr int C_NCH    = 28;     // 224 / C_RW
constexpr int C_NW     = 224;
constexpr int C_SIGP   = 128;    // padded slots
constexpr int C_M      = 512;    // m per piece
constexpr int C_NP     = 7;      // max pieces
constexpr int C_SQ     = 64;     // staged quads per row per phase (8 KB total)

typedef float v2f __attribute__((ext_vector_type(2)));
typedef float v4f __attribute__((ext_vector_type(4)));

// Replicate numpy: scales = logspace(log10(2), log10(204), 128).astype(f32);
// K = ceil(16*s + 1); d = (4094-K)//2; a = s * (16/4095) in double.
__device__ __forceinline__ void scale_params(int i, float& s32, int& K, int& d, double& a) {
  const double l2   = log10(2.0);
  const double l204 = log10(204.0);
  double step = (l204 - l2) / 127.0;
  double e = (i == 127) ? l204 : ((double)i * step + l2);
  double sv = pow(10.0, e);
  s32 = (float)sv;
  double sp = (double)s32;
  K = (int)ceil(sp * 16.0 + 1.0);
  d = (4094 - K) >> 1;
  a = sp * (16.0 / 4095.0);
}

// ---------------- build composite kernels H (+fused OT zero & xpQ build) -------------
// grid (128, 10): cls<9 -> H row; cls==9 -> zero OT strip + build xpQ strip.
__global__ __launch_bounds__(256) void k_build_H(const float* __restrict__ int_psi,
                                                 const float* __restrict__ x,
                                                 float* __restrict__ Hbuf,
                                                 int* __restrict__ meta,
                                                 float* __restrict__ xpQ,
                                                 float* __restrict__ OT) {
  int i   = blockIdx.x;   // scale (or strip index for cls==9)
  int cls = blockIdx.y;   // class

  if (cls == 9) {
    // zero OT strip: 128 strips x 7168 float4
    float4* otz = (float4*)OT + (long long)i * 7168;
    float4 z4 = make_float4(0.f, 0.f, 0.f, 0.f);
    for (int q = threadIdx.x; q < 7168; q += 256) otz[q] = z4;
    // build xpQ strip: 128 strips x 8192 floats; slot-interleaved, reflect pad
    for (int q = threadIdx.x; q < 8192; q += 256) {
      int idx = i * 8192 + q;
      int r   = idx & 127;
      int p   = idx >> 7;
      int g   = r >> 2;       // b
      int e   = r & 3;        // c (e==3 -> pad)
      float val = 0.f;
      if (e < 3 && p < C_TP) {
        int t = p - 2047;
        if (t < 0) t = -t;                 // x[2047-p]
        else if (t > 4095) t = 8190 - t;   // x[10237-p]
        val = x[(g * 4096 + t) * 3 + e];
      }
      xpQ[idx] = val;
    }
    return;
  }

  float s32; int K, d; double a;
  scale_params(i, s32, K, d, a);

  int wr = (cls < 7) ? ((cls == 0) ? 7 : cls) : ((cls == 7) ? 0 : 223);
  double ks = 4096.0 / 224.0;
  double sf = ((double)wr + 0.5) * ks - 0.5;
  int t_lo = (int)floor(sf - ks) + 1;
  int t_hi = (int)ceil(sf + ks) - 1;
  if (t_lo < 0) t_lo = 0;
  if (t_hi > 4095) t_hi = 4095;
  int nt  = t_hi - t_lo + 1;   // <= 37
  int npv = nt + 1;            // conv-point weights

  int p_lo = t_lo + d;
  int Lh   = K + npv - 1;
  int kr   = (cls == 0) ? 1 : ((cls == 8) ? 31 : 0);
  int off0 = p_lo - 128 * kr;
  int shift = off0 & 3;
  int offA  = off0 - shift;
  int rowLen = (shift + Lh + 3) & ~3;

  __shared__ double Wt_sh[40];
  __shared__ float  v_shf[40];
  __shared__ float  kern_sh[3352];

  // zero only the guard regions (data region [g0,g1) fully overwritten below)
  float* rowFull = Hbuf + (long long)(i * C_NCLS + cls) * C_HSTRIDE;
  int g0 = C_HGUARD + shift;
  int g1 = g0 + Lh;
  for (int q = threadIdx.x; q < g0; q += 256) rowFull[q] = 0.f;
  for (int q = g1 + threadIdx.x; q < (int)C_HSTRIDE; q += 256) rowFull[q] = 0.f;

  if (threadIdx.x == 0) {
    double Z = 0.0;
    for (int t = 0; t < nt; ++t) {
      double wv = 1.0 - fabs(sf - (double)(t + t_lo)) / ks;
      if (wv < 0.0) wv = 0.0;
      Wt_sh[t] = wv; Z += wv;
    }
    for (int t = 0; t < nt; ++t) Wt_sh[t] = Wt_sh[t] / Z;
    double sq = sqrt((double)s32);
    // v[p_lo + q] = -sqrt(s) * (Wt[q-1] - Wt[q])   (built in double, used f32)
    for (int q = 0; q < 40; ++q) {
      double wm1 = (q >= 1 && q <= nt)  ? Wt_sh[q - 1] : 0.0;
      double w0  = (q < nt)             ? Wt_sh[q]     : 0.0;
      v_shf[q] = (float)(-sq * (wm1 - w0));
    }
  }

  // flipped gathered wavelet: kernW[tau] = int_psi[clip(floor((K-1-tau)/a))]
  float* kernp = kern_sh + 40;
  int fillN = K + 80;
  for (int q = threadIdx.x; q < fillN; q += 256) {
    int tau = q - 40;
    float kv = 0.f;
    if (tau >= 0 && tau < K) {
      int u = K - 1 - tau;
      int jj = (int)floor((double)u / a);
      jj = jj < 0 ? 0 : (jj > 4095 ? 4095 : jj);
      kv = int_psi[jj];
    }
    kern_sh[q] = kv;
  }
  __syncthreads();

  float* row = rowFull + C_HGUARD;
  for (int q = threadIdx.x; q < Lh; q += 256) {
    float acc = 0.f;
    for (int t = 0; t < npv; ++t) acc += v_shf[t] * kernp[q - t];
    row[shift + q] = acc;
  }
  if (threadIdx.x == 0) {
    meta[(i * C_NCLS + cls) * 2 + 0] = offA;
    meta[(i * C_NCLS + cls) * 2 + 1] = rowLen;
  }
}

// ---------------- main: OT[scale][w][slot] += sum_{m in piece} xp[m][slot]*H_w[m] ------
// grid (piece, chunk, scale'), scale' reversed so heavy scales dispatch first.
// ONE wave; iteration-granular half-wave m-split; lane owns slots {g,g+32,g+64,g+96}.
__global__ __launch_bounds__(64, 4) void k_cwt_main(const float* __restrict__ xpQ,
                                                    const float* __restrict__ Hbuf,
                                                    const int* __restrict__ meta,
                                                    float* __restrict__ OT) {
  int piece = blockIdx.x;           // 0..6
  int chunk = blockIdx.y;           // 0..27
  int i     = 127 - blockIdx.z;     // heavy scales first
  int lane  = threadIdx.x;          // 0..63
  int g     = lane & 31;
  int half  = lane >> 5;

  __shared__ v4f Hs[C_RW][C_SQ];    // 8 KB (per phase)

  v2f accL[C_RW], accH[C_RW];
  const float* rowP[C_RW];
  int startj[C_RW];
  int U0 = 0x7fffffff, U1 = 0;
#pragma unroll
  for (int j = 0; j < C_RW; ++j) {
    accL[j] = (v2f){0.f, 0.f};
    accH[j] = (v2f){0.f, 0.f};
    int w = chunk * C_RW + j;
    int cls = (w == 0) ? 7 : ((w == 223) ? 8 : (w % 7));
    int k = w / 7;
    int base = i * C_NCLS + cls;
    int offA = meta[base * 2 + 0];
    int rl   = meta[base * 2 + 1];
    int start = offA + 128 * k;           // 4-aligned by construction
    startj[j] = start;
    if (start < U0) U0 = start;
    if (start + rl > U1) U1 = start + rl;
    rowP[j] = Hbuf + (long long)base * C_HSTRIDE;
  }

  int m0 = U0 + piece * C_M;
  int m1 = m0 + C_M; if (m1 > U1) m1 = U1;
  if (m0 >= m1) return;                  // uniform across block

  int len = m1 - m0;
  int nIt = (len + 7) >> 3;              // 8-m steps (<=64)

  // two phases of <=32 steps; phase stages quads [2*it0, 2*it1) (<=64 = 8 KB)
  for (int ph = 0; ph < 2; ++ph) {
    int it0 = ph << 5;
    if (it0 >= nIt) break;
    int it1 = nIt < it0 + 32 ? nIt : it0 + 32;
    int qn  = 2 * (it1 - it0);

    // ---- stage H quads for this phase ----
    // staged float idx within row <= HGUARD + (m1+7-startj) <= 3617 < 3776:
    // always row data or zero guard. relS >= 160-136 > 0.
#pragma unroll
    for (int j = 0; j < C_RW; ++j) {
      const float* src = rowP[j] + (C_HGUARD + m0 - startj[j]) + 8 * it0;
      if (lane < qn) Hs[j][lane] = *(const v4f*)(src + 4 * lane);
    }
    __syncthreads();

    // ---- inner loop: half h covers m0+8it+4h..+3; quad index 2(it-it0)+half ----
    const float* xr = xpQ + ((long long)(m0 + 8 * it0 + 4 * half) << 7) + (g << 2);
#pragma unroll 2
    for (int it = it0; it < it1; ++it) {
      v4f xv0 = *(const v4f*)(xr);
      v4f xv1 = *(const v4f*)(xr + 128);
      v4f xv2 = *(const v4f*)(xr + 256);
      v4f xv3 = *(const v4f*)(xr + 384);
      xr += 1024;
      int lq = 2 * (it - it0) + half;
#pragma unroll
      for (int j = 0; j < C_RW; ++j) {
        v4f h = Hs[j][lq];
        accL[j] += xv0.xy * h.x; accH[j] += xv0.zw * h.x;
        accL[j] += xv1.xy * h.y; accH[j] += xv1.zw * h.y;
        accL[j] += xv2.xy * h.z; accH[j] += xv2.zw * h.z;
        accL[j] += xv3.xy * h.w; accH[j] += xv3.zw * h.w;
      }
    }
    __syncthreads();   // protect Hs before next phase overwrites
  }

  // ---- combine halves, then coalesced fp32 atomics (lanes 0-31, 4 batches of 32) ----
#pragma unroll
  for (int j = 0; j < C_RW; ++j) {
    float s0 = accL[j].x, s1 = accL[j].y, s2 = accH[j].x, s3 = accH[j].y;
    s0 += __shfl_xor(s0, 32);
    s1 += __shfl_xor(s1, 32);
    s2 += __shfl_xor(s2, 32);
    s3 += __shfl_xor(s3, 32);
    if (lane < 32) {
      int w = chunk * C_RW + j;
      float* dst = OT + ((long long)i * C_NW + w) * C_SIGP;
      atomicAdd(dst + g,      s0);     // slots  0..31  contiguous across lanes
      atomicAdd(dst + 32 + g, s1);     // slots 32..63
      atomicAdd(dst + 64 + g, s2);     // slots 64..95
      atomicAdd(dst + 96 + g, s3);     // slots 96..127 (pad)
    }
  }
}

// ---------------- final: scale-dim bilinear upsample 128->224 + layout ----------------
__global__ __launch_bounds__(256) void k_final(const float* __restrict__ OT,
                                               float* __restrict__ out) {
  int wt = blockIdx.x;    // 0..27
  int h  = blockIdx.y;    // 0..223

  float inv = 128.0f / 224.0f;               // f32 like jax
  float sg = ((float)h + 0.5f) * inv - 0.5f;
  float sgf = floorf(sg);
  int s0 = (int)sgf;
  float fr = sg - sgf;
  int r0, r1;
  if (s0 < 0)        { r0 = 0;   r1 = 0;   fr = 0.f; }
  else if (s0 >= 127){ r0 = 127; r1 = 127; fr = 0.f; }
  else               { r0 = s0;  r1 = s0 + 1; }

  __shared__ float sh0[8 * 132];
  __shared__ float sh1[8 * 132];
  for (int q = threadIdx.x; q < 1024; q += 256) {
    int wp  = q >> 7;
    int sg2 = q & 127;
    int wg  = wt * 8 + wp;
    sh0[wp * 132 + sg2] = OT[((long long)r0 * C_NW + wg) * C_SIGP + sg2];
    sh1[wp * 132 + sg2] = OT[((long long)r1 * C_NW + wg) * C_SIGP + sg2];
  }
  __syncthreads();

  int b  = threadIdx.x >> 3;    // 0..31
  int wp = threadIdx.x & 7;     // 0..7
  int obase = ((b * 224 + h) * 224 + wt * 8 + wp) * 3;
#pragma unroll
  for (int c = 0; c < 3; ++c) {
    int sidx = wp * 132 + c * 32 + b;
    float a0 = sh0[sidx];
    float a1 = sh1[sidx];
    out[obase + c] = (1.0f - fr) * a0 + fr * a1;
  }
}

// ---------------- launch ----------------
extern "C" void kernel_launch(void* const* d_in, const int* in_sizes, int n_in,
                              void* d_out, int out_size, void* d_ws, size_t ws_size,
                              hipStream_t stream) {
  const float* x       = (const float*)d_in[0];   // (32,4096,3) f32
  const float* int_psi = (const float*)d_in[1];   // (4096,) f32
  float* out = (float*)d_out;

  // workspace layout: xpQ (4 MB) | Hbuf (17.4 MB) | meta (9 KB) | OT (14.7 MB)
  float* xpQ  = (float*)d_ws;                                   // 8192*128 floats
  float* Hbuf = xpQ + (long long)C_XROWS * C_SIGP;              // 1152*3776 floats
  int*   meta = (int*)(Hbuf + (long long)128 * C_NCLS * C_HSTRIDE); // 2304 ints
  float* OT   = (float*)(meta + 2304);                          // 128*224*128 floats

  k_build_H<<<dim3(128, 10), dim3(256), 0, stream>>>(int_psi, x, Hbuf, meta, xpQ, OT);
  k_cwt_main<<<dim3(C_NP, C_NCH, 128), dim3(64), 0, stream>>>(xpQ, Hbuf, meta, OT);
  k_final<<<dim3(28, 224), dim3(256), 0, stream>>>(OT, out);
}